// Round 1
// baseline (1046.420 us; speedup 1.0000x reference)
//
#include <hip/hip_runtime.h>
#include <math.h>

#define EIG_REG 1e-6f

// ---------------------------------------------------------------------------
// trace(sqrt(M)) for symmetric 3x3 M via closed-form eigenvalues (Cardano).
// Matches reference: eigvalsh(M), clip(ev,0), sum sqrt.
// ---------------------------------------------------------------------------
__device__ __forceinline__ float trace_sqrt_eig3(float m00, float m01, float m02,
                                                 float m11, float m12, float m22)
{
    float q  = (m00 + m11 + m22) * (1.0f / 3.0f);
    float p1 = m01 * m01 + m02 * m02 + m12 * m12;
    float a0 = m00 - q, a1 = m11 - q, a2 = m22 - q;
    float p2 = a0 * a0 + a1 * a1 + a2 * a2 + 2.0f * p1;
    float p  = sqrtf(fmaxf(p2, 0.0f) * (1.0f / 6.0f));
    if (p < 1e-10f) {
        // nearly scalar matrix: all eigenvalues == q
        return 3.0f * sqrtf(fmaxf(q, 0.0f));
    }
    float ip  = 1.0f / p;
    float b00 = a0 * ip, b11 = a1 * ip, b22 = a2 * ip;
    float b01 = m01 * ip, b02 = m02 * ip, b12 = m12 * ip;
    float detB = b00 * (b11 * b22 - b12 * b12)
               - b01 * (b01 * b22 - b12 * b02)
               + b02 * (b01 * b12 - b11 * b02);
    float r = 0.5f * detB;
    r = fminf(fmaxf(r, -1.0f), 1.0f);
    float phi = acosf(r) * (1.0f / 3.0f);
    float e1 = q + 2.0f * p * cosf(phi);
    float e3 = q + 2.0f * p * cosf(phi + 2.0943951023931953f); // +2*pi/3
    float e2 = 3.0f * q - e1 - e3;
    return sqrtf(fmaxf(e1, 0.0f)) + sqrtf(fmaxf(e2, 0.0f)) + sqrtf(fmaxf(e3, 0.0f));
}

// ---------------------------------------------------------------------------
// Per-Gaussian prep:
//   A side: tr(cov_A), sA = sqrtm(cov_A + 1e-6 I) via cyclic Jacobi (3x3)
//   B side: tr(cov_B), v init = 1  (log_v = 0)
// ---------------------------------------------------------------------------
__global__ __launch_bounds__(256) void prep_kernel(
    const float* __restrict__ covA, const float* __restrict__ covB,
    int Na, int Nb,
    float* __restrict__ sA, float* __restrict__ trA, float* __restrict__ trB,
    float* __restrict__ v)
{
    int i = blockIdx.x * blockDim.x + threadIdx.x;
    if (i < Nb) {
        const float* c = covB + (size_t)i * 9;
        trB[i] = c[0] + c[4] + c[8];
        v[i]   = 1.0f;
    }
    if (i < Na) {
        const float* c = covA + (size_t)i * 9;
        float A[3][3];
        A[0][0] = c[0]; A[0][1] = c[1]; A[0][2] = c[2];
        A[1][0] = c[3]; A[1][1] = c[4]; A[1][2] = c[5];
        A[2][0] = c[6]; A[2][1] = c[7]; A[2][2] = c[8];
        trA[i] = A[0][0] + A[1][1] + A[2][2];
        A[0][0] += EIG_REG; A[1][1] += EIG_REG; A[2][2] += EIG_REG;

        float V[3][3] = {{1.f,0.f,0.f},{0.f,1.f,0.f},{0.f,0.f,1.f}};
        const int pp[3] = {0, 0, 1}, qq[3] = {1, 2, 2};
        #pragma unroll
        for (int sweep = 0; sweep < 8; ++sweep) {
            #pragma unroll
            for (int k3 = 0; k3 < 3; ++k3) {
                int p = pp[k3], q = qq[k3];
                float apq = A[p][q];
                if (fabsf(apq) <= 1e-20f) continue;
                float theta = (A[q][q] - A[p][p]) / (2.0f * apq);
                float t  = copysignf(1.0f, theta) /
                           (fabsf(theta) + sqrtf(theta * theta + 1.0f));
                float cc = 1.0f / sqrtf(t * t + 1.0f);
                float ss = t * cc;
                float app = A[p][p], aqq = A[q][q];
                A[p][p] = app - t * apq;
                A[q][q] = aqq + t * apq;
                A[p][q] = A[q][p] = 0.0f;
                int rr = 3 - p - q;
                float arp = A[rr][p], arq = A[rr][q];
                A[rr][p] = A[p][rr] = cc * arp - ss * arq;
                A[rr][q] = A[q][rr] = ss * arp + cc * arq;
                #pragma unroll
                for (int k = 0; k < 3; ++k) {
                    float vkp = V[k][p], vkq = V[k][q];
                    V[k][p] = cc * vkp - ss * vkq;
                    V[k][q] = ss * vkp + cc * vkq;
                }
            }
        }
        float sw0 = sqrtf(fmaxf(A[0][0], 0.0f));
        float sw1 = sqrtf(fmaxf(A[1][1], 0.0f));
        float sw2 = sqrtf(fmaxf(A[2][2], 0.0f));
        float* o = sA + (size_t)i * 9;
        #pragma unroll
        for (int r = 0; r < 3; ++r)
            #pragma unroll
            for (int cI = 0; cI < 3; ++cI)
                o[r * 3 + cI] = V[r][0] * sw0 * V[cI][0]
                              + V[r][1] * sw1 * V[cI][1]
                              + V[r][2] * sw2 * V[cI][2];
    }
}

// ---------------------------------------------------------------------------
// Cost/kernel matrix: K[a,b] = exp(-C[a,b]); also writes KT[b,a] via LDS tile.
// C = ||muA-muB||^2 + trA + trB - 2*tr(sqrt(sA cov_B sA + 1e-6 I))
// Block = 256 threads handling a 32x32 (a,b) tile.
// ---------------------------------------------------------------------------
__global__ __launch_bounds__(256) void cost_kernel(
    const float* __restrict__ muA, const float* __restrict__ muB,
    const float* __restrict__ covB, const float* __restrict__ sA,
    const float* __restrict__ trA, const float* __restrict__ trB,
    int Na, int Nb,
    float* __restrict__ K, float* __restrict__ KT)
{
    __shared__ float tile[32][33];
    int tx = threadIdx.x & 31;   // b within tile
    int ty = threadIdx.x >> 5;   // 0..7 (a stride 8)
    int a0 = blockIdx.y * 32;
    int b0 = blockIdx.x * 32;
    int b  = b0 + tx;

    float cb[9], mb0 = 0.f, mb1 = 0.f, mb2 = 0.f, trb = 0.f;
    bool bvalid = (b < Nb);
    if (bvalid) {
        const float* c = covB + (size_t)b * 9;
        #pragma unroll
        for (int k = 0; k < 9; ++k) cb[k] = c[k];
        mb0 = muB[(size_t)b * 3 + 0];
        mb1 = muB[(size_t)b * 3 + 1];
        mb2 = muB[(size_t)b * 3 + 2];
        trb = trB[b];
    } else {
        #pragma unroll
        for (int k = 0; k < 9; ++k) cb[k] = 0.f;
    }

    #pragma unroll
    for (int r = 0; r < 4; ++r) {
        int ay = ty + r * 8;
        int a  = a0 + ay;
        float kval = 0.0f;
        if (a < Na && bvalid) {
            const float* s = sA + (size_t)a * 9;
            float S[3][3];
            S[0][0]=s[0]; S[0][1]=s[1]; S[0][2]=s[2];
            S[1][0]=s[3]; S[1][1]=s[4]; S[1][2]=s[5];
            S[2][0]=s[6]; S[2][1]=s[7]; S[2][2]=s[8];
            float Cb[3][3];
            Cb[0][0]=cb[0]; Cb[0][1]=cb[1]; Cb[0][2]=cb[2];
            Cb[1][0]=cb[3]; Cb[1][1]=cb[4]; Cb[1][2]=cb[5];
            Cb[2][0]=cb[6]; Cb[2][1]=cb[7]; Cb[2][2]=cb[8];
            // T = S * Cb ; M = T * S  (symmetric)
            float T[3][3];
            #pragma unroll
            for (int i = 0; i < 3; ++i)
                #pragma unroll
                for (int j = 0; j < 3; ++j)
                    T[i][j] = S[i][0]*Cb[0][j] + S[i][1]*Cb[1][j] + S[i][2]*Cb[2][j];
            float m00 = T[0][0]*S[0][0] + T[0][1]*S[1][0] + T[0][2]*S[2][0] + EIG_REG;
            float m01 = T[0][0]*S[0][1] + T[0][1]*S[1][1] + T[0][2]*S[2][1];
            float m02 = T[0][0]*S[0][2] + T[0][1]*S[1][2] + T[0][2]*S[2][2];
            float m11 = T[1][0]*S[0][1] + T[1][1]*S[1][1] + T[1][2]*S[2][1] + EIG_REG;
            float m12 = T[1][0]*S[0][2] + T[1][1]*S[1][2] + T[1][2]*S[2][2];
            float m22 = T[2][0]*S[0][2] + T[2][1]*S[1][2] + T[2][2]*S[2][2] + EIG_REG;
            float trsq = trace_sqrt_eig3(m00, m01, m02, m11, m12, m22);

            float d0 = muA[(size_t)a*3+0] - mb0;
            float d1 = muA[(size_t)a*3+1] - mb1;
            float d2 = muA[(size_t)a*3+2] - mb2;
            float mean = d0*d0 + d1*d1 + d2*d2;
            float Cv = mean + trA[a] + trb - 2.0f * trsq;
            kval = expf(-Cv);
            K[(size_t)a * Nb + b] = kval;   // coalesced (tx == b)
        }
        tile[ay][tx] = kval;
    }
    __syncthreads();
    // transposed write: KT[b, a], coalesced in a (= tx)
    #pragma unroll
    for (int r = 0; r < 4; ++r) {
        int by = ty + r * 8;
        int bb = b0 + by;
        int aa = a0 + tx;
        if (bb < Nb && aa < Na)
            KT[(size_t)bb * Na + aa] = tile[tx][by];
    }
}

// ---------------------------------------------------------------------------
// One Sinkhorn half-step: out[row] = w[row] / sum_j Mat[row, j] * x[j]
// One block (256 threads) per row.
// ---------------------------------------------------------------------------
__global__ __launch_bounds__(256) void rowdiv_kernel(
    const float* __restrict__ Mat, const float* __restrict__ x,
    const float* __restrict__ w, int ncols, float* __restrict__ out)
{
    __shared__ float red[4];
    int row = blockIdx.x;
    const float* mrow = Mat + (size_t)row * ncols;
    float s = 0.0f;
    for (int j = threadIdx.x; j < ncols; j += 256)
        s += mrow[j] * x[j];
    #pragma unroll
    for (int off = 32; off > 0; off >>= 1)
        s += __shfl_down(s, off, 64);
    if ((threadIdx.x & 63) == 0) red[threadIdx.x >> 6] = s;
    __syncthreads();
    if (threadIdx.x == 0)
        out[row] = w[row] / (red[0] + red[1] + red[2] + red[3]);
}

// ---------------------------------------------------------------------------
// Final pass 1: per-row partials of  sum(P*C)  and  max(P),  P = u*K*v,
// C = -log(K)  (EPSILON == 1).  Entries with K ~ 0 contribute 0 to the sum.
// ---------------------------------------------------------------------------
__global__ __launch_bounds__(256) void final_partial(
    const float* __restrict__ K, const float* __restrict__ u,
    const float* __restrict__ v, int Nb,
    float* __restrict__ psum, float* __restrict__ pmax)
{
    __shared__ float rs[4], rm[4];
    int a = blockIdx.x;
    const float* row = K + (size_t)a * Nb;
    float ua = u[a];
    float s = 0.0f, m = 0.0f;
    for (int b = threadIdx.x; b < Nb; b += 256) {
        float k = row[b];
        float P = ua * k * v[b];
        m = fmaxf(m, P);
        if (k > 1e-37f) {
            float C = -logf(k);
            s += P * C;
        }
    }
    #pragma unroll
    for (int off = 32; off > 0; off >>= 1) {
        s += __shfl_down(s, off, 64);
        m = fmaxf(m, __shfl_down(m, off, 64));
    }
    if ((threadIdx.x & 63) == 0) { rs[threadIdx.x >> 6] = s; rm[threadIdx.x >> 6] = m; }
    __syncthreads();
    if (threadIdx.x == 0) {
        psum[a] = rs[0] + rs[1] + rs[2] + rs[3];
        pmax[a] = fmaxf(fmaxf(rm[0], rm[1]), fmaxf(rm[2], rm[3]));
    }
}

__global__ __launch_bounds__(256) void final_reduce(
    const float* __restrict__ psum, const float* __restrict__ pmax,
    int n, float* __restrict__ out)
{
    __shared__ float rs[4], rm[4];
    float s = 0.0f, m = 0.0f;
    for (int i = threadIdx.x; i < n; i += 256) {
        s += psum[i];
        m = fmaxf(m, pmax[i]);
    }
    #pragma unroll
    for (int off = 32; off > 0; off >>= 1) {
        s += __shfl_down(s, off, 64);
        m = fmaxf(m, __shfl_down(m, off, 64));
    }
    if ((threadIdx.x & 63) == 0) { rs[threadIdx.x >> 6] = s; rm[threadIdx.x >> 6] = m; }
    __syncthreads();
    if (threadIdx.x == 0) {
        float S = rs[0] + rs[1] + rs[2] + rs[3];
        float M = fmaxf(fmaxf(rm[0], rm[1]), fmaxf(rm[2], rm[3]));
        out[0] = S / M;
    }
}

// ---------------------------------------------------------------------------
extern "C" void kernel_launch(void* const* d_in, const int* in_sizes, int n_in,
                              void* d_out, int out_size, void* d_ws, size_t ws_size,
                              hipStream_t stream)
{
    const float* muA  = (const float*)d_in[0];
    const float* covA = (const float*)d_in[1];
    const float* wA   = (const float*)d_in[2];
    const float* muB  = (const float*)d_in[3];
    const float* covB = (const float*)d_in[4];
    const float* wB   = (const float*)d_in[5];
    int Na = in_sizes[0] / 3;
    int Nb = in_sizes[3] / 3;

    float* W = (float*)d_ws;
    size_t NN = (size_t)Na * Nb;
    float* K    = W;
    float* KT   = K + NN;
    float* sA   = KT + NN;
    float* trA  = sA + (size_t)Na * 9;
    float* trB  = trA + Na;
    float* u    = trB + Nb;
    float* v    = u + Na;
    float* psum = v + Nb;
    float* pmax = psum + Na;

    int nmax = Na > Nb ? Na : Nb;
    prep_kernel<<<(nmax + 255) / 256, 256, 0, stream>>>(covA, covB, Na, Nb,
                                                        sA, trA, trB, v);
    dim3 cg((Nb + 31) / 32, (Na + 31) / 32);
    cost_kernel<<<cg, 256, 0, stream>>>(muA, muB, covB, sA, trA, trB,
                                        Na, Nb, K, KT);
    for (int it = 0; it < 100; ++it) {
        rowdiv_kernel<<<Na, 256, 0, stream>>>(K,  v, wA, Nb, u);
        rowdiv_kernel<<<Nb, 256, 0, stream>>>(KT, u, wB, Na, v);
    }
    final_partial<<<Na, 256, 0, stream>>>(K, u, v, Nb, psum, pmax);
    final_reduce<<<1, 256, 0, stream>>>(psum, pmax, Na, (float*)d_out);
}